// Round 12
// baseline (72.507 us; speedup 1.0000x reference)
//
#include <hip/hip_runtime.h>

#define BS  16
#define NN  256
#define HID 128

// 512 blocks: XCD x gets swz in [64x, 64x+64) = batches 2x, 2x+1.
__device__ __forceinline__ int xcd_swz(int bid) {
    return (bid & 7) * 64 + (bid >> 3);
}

// ---------------------------------------------------------------------------
// K1a: h = x@W_fc + b_fc. 512 blocks x 512 threads, 8 rows/block, thread
// (k, q) computes rows 2q, 2q+1. x rows are wave-uniform -> SCALAR loads
// (SMEM pipe); weights per-lane VMEM. ZERO LDS.
// ---------------------------------------------------------------------------
__global__ __launch_bounds__(512, 4) void gat_k1a(
    const float* __restrict__ x, const float* __restrict__ W_fc,
    const float* __restrict__ b_fc, float* __restrict__ h)
{
    const int tid = threadIdx.x;
    const int k   = tid & 127;
    const int q   = tid >> 7;                 // 0..3
    const int swz = xcd_swz(blockIdx.x);
    const int r0  = swz * 8;                  // flat row = b*NN + n0

    const float* xr0 = x + (r0 + 2 * q) * HID;   // wave-uniform
    const float* xr1 = xr0 + HID;

    const float bf = b_fc[k];
    float a0a = bf, a0b = 0.f, a1a = 0.f, a1b = 0.f;
    #pragma unroll 4
    for (int d0 = 0; d0 < HID; d0 += 8) {
        float w[8];
        #pragma unroll
        for (int t = 0; t < 8; ++t) w[t] = W_fc[(d0 + t) * HID + k];
        const float4 x00 = *(const float4*)(xr0 + d0);       // s_load_dwordx4
        const float4 x01 = *(const float4*)(xr0 + d0 + 4);
        const float4 x10 = *(const float4*)(xr1 + d0);
        const float4 x11 = *(const float4*)(xr1 + d0 + 4);
        a0a += x00.x * w[0] + x00.y * w[1] + x00.z * w[2] + x00.w * w[3];
        a0b += x01.x * w[4] + x01.y * w[5] + x01.z * w[6] + x01.w * w[7];
        a1a += x10.x * w[0] + x10.y * w[1] + x10.z * w[2] + x10.w * w[3];
        a1b += x11.x * w[4] + x11.y * w[5] + x11.z * w[6] + x11.w * w[7];
    }
    h[(r0 + 2 * q + 0) * HID + k] = a0a + a0b;
    h[(r0 + 2 * q + 1) * HID + k] = a1a + a1b;
}

// ---------------------------------------------------------------------------
// K1b: ai/aj/g from h. h is a kernel INPUT here (written by K1a, coherent
// across the launch boundary) -> h rows via SCALAR loads. ZERO LDS.
// q0/q1 -> ai rows 0-3/4-7; q2/q3 -> aj rows 0-3/4-7 (stored transposed
// [b][k][n] direct from registers); all q also compute g rows 2q, 2q+1.
// ---------------------------------------------------------------------------
__global__ __launch_bounds__(512, 4) void gat_k1b(
    const float* __restrict__ h, const float* __restrict__ W_a1,
    const float* __restrict__ b_a1, const float* __restrict__ W_out,
    float* __restrict__ aiT, float* __restrict__ ajT, float* __restrict__ g)
{
    const int tid = threadIdx.x;
    const int k   = tid & 127;
    const int q   = tid >> 7;                 // 0..3
    const int swz = xcd_swz(blockIdx.x);
    const int r0  = swz * 8;                  // flat row = b*NN + n0
    const int b   = r0 >> 8;
    const int n0  = r0 & 255;

    // ---- part 1: ai or aj for 4 rows ----
    {
        const int is_aj = q >> 1;
        const int rb    = (q & 1) * 4;
        const float* Wp = W_a1 + is_aj * HID * HID;
        const float bias = is_aj ? 0.f : b_a1[k];
        const float* hr0 = h + (r0 + rb + 0) * HID;   // wave-uniform
        const float* hr1 = h + (r0 + rb + 1) * HID;
        const float* hr2 = h + (r0 + rb + 2) * HID;
        const float* hr3 = h + (r0 + rb + 3) * HID;

        float acc[4] = {bias, bias, bias, bias};
        #pragma unroll 4
        for (int d0 = 0; d0 < HID; d0 += 4) {
            float w[4];
            #pragma unroll
            for (int t = 0; t < 4; ++t) w[t] = Wp[(d0 + t) * HID + k];
            const float4 h0 = *(const float4*)(hr0 + d0);
            const float4 h1 = *(const float4*)(hr1 + d0);
            const float4 h2 = *(const float4*)(hr2 + d0);
            const float4 h3 = *(const float4*)(hr3 + d0);
            acc[0] += h0.x * w[0] + h0.y * w[1] + h0.z * w[2] + h0.w * w[3];
            acc[1] += h1.x * w[0] + h1.y * w[1] + h1.z * w[2] + h1.w * w[3];
            acc[2] += h2.x * w[0] + h2.y * w[1] + h2.z * w[2] + h2.w * w[3];
            acc[3] += h3.x * w[0] + h3.y * w[1] + h3.z * w[2] + h3.w * w[3];
        }
        const float4 v = {acc[0], acc[1], acc[2], acc[3]};
        float* dst = (is_aj ? ajT : aiT) + (b * HID + k) * NN + n0 + rb;
        *(float4*)dst = v;
    }

    // ---- part 2: g rows 2q, 2q+1 = h @ W_out ----
    {
        const float* gr0 = h + (r0 + 2 * q) * HID;    // wave-uniform
        const float* gr1 = gr0 + HID;
        float o0a = 0.f, o0b = 0.f, o1a = 0.f, o1b = 0.f;
        #pragma unroll 4
        for (int d0 = 0; d0 < HID; d0 += 8) {
            float w[8];
            #pragma unroll
            for (int t = 0; t < 8; ++t) w[t] = W_out[(d0 + t) * HID + k];
            const float4 h00 = *(const float4*)(gr0 + d0);
            const float4 h01 = *(const float4*)(gr0 + d0 + 4);
            const float4 h10 = *(const float4*)(gr1 + d0);
            const float4 h11 = *(const float4*)(gr1 + d0 + 4);
            o0a += h00.x * w[0] + h00.y * w[1] + h00.z * w[2] + h00.w * w[3];
            o0b += h01.x * w[4] + h01.y * w[5] + h01.z * w[6] + h01.w * w[7];
            o1a += h10.x * w[0] + h10.y * w[1] + h10.z * w[2] + h10.w * w[3];
            o1b += h11.x * w[4] + h11.y * w[5] + h11.z * w[6] + h11.w * w[7];
        }
        g[(r0 + 2 * q + 0) * HID + k] = o0a + o0b;
        g[(r0 + 2 * q + 1) * HID + k] = o1a + o1b;
    }
}

// ---------------------------------------------------------------------------
// K2: unchanged (R11). 512 blocks, 512 threads, 8-row i-tile. Phase A with
// hoisted row-independent sum; softmax 1 row/wave; phase B j-quartered.
// ---------------------------------------------------------------------------
__global__ __launch_bounds__(512, 4) void gat_k2(
    const float* __restrict__ aiT, const float* __restrict__ ajT,
    const float* __restrict__ g,  const int* __restrict__ adj,
    const float* __restrict__ w_a2, const float* __restrict__ b_a2,
    const float* __restrict__ b_out, float* __restrict__ out)
{
    __shared__ __align__(16) float aiw[HID][8];          // 4KB, [k][row]
    __shared__ __align__(16) float w2s[HID];
    __shared__ __align__(16) float ep[8][NN];            // 8KB
    __shared__ __align__(16) float red[4][8][HID];       // 16KB

    const int tid = threadIdx.x;
    const int swz = xcd_swz(blockIdx.x);
    const int b   = swz >> 5;
    const int i0  = (swz & 31) * 8;
    const int wv  = tid >> 6, lane = tid & 63;

    for (int t = tid; t < HID * 8; t += 512) {
        const int kk = t >> 3, r = t & 7;
        aiw[kk][r] = aiT[(b * HID + kk) * NN + i0 + r];
    }
    if (tid < HID) w2s[tid] = w_a2[tid];
    __syncthreads();

    // ---- phase A: e[8 rows][j], wave covers 32 j x all 8 rows ----
    const int jj = 32 * wv + (lane & 31);
    const int rg = lane >> 5;                 // rows 4rg .. 4rg+3
    {
        int am[4];
        #pragma unroll
        for (int r = 0; r < 4; ++r)
            am[r] = adj[(b * NN + i0 + 4 * rg + r) * NN + jj];

        const float* ajp = ajT + b * HID * NN + jj;
        float acc[4] = {0.f, 0.f, 0.f, 0.f};
        float saw = 0.f;                      // sum_k a*wk (row-independent)
        #pragma unroll 8
        for (int kk = 0; kk < HID; ++kk) {
            const float a   = ajp[kk * NN];
            const float4 f4 = *(const float4*)&aiw[kk][4 * rg];
            const float wk  = w2s[kk];
            saw = __builtin_fmaf(a, wk, saw);
            acc[0] = __builtin_fmaf(fmaxf(f4.x, -a), wk, acc[0]);
            acc[1] = __builtin_fmaf(fmaxf(f4.y, -a), wk, acc[1]);
            acc[2] = __builtin_fmaf(fmaxf(f4.z, -a), wk, acc[2]);
            acc[3] = __builtin_fmaf(fmaxf(f4.w, -a), wk, acc[3]);
        }
        const float base = saw + b_a2[0];
        #pragma unroll
        for (int r = 0; r < 4; ++r)
            ep[4 * rg + r][jj] = am[r] ? acc[r] + base : -1e9f;
    }
    __syncthreads();

    // ---- softmax: wave wv owns row wv ----
    {
        float4 e4 = *(const float4*)&ep[wv][4 * lane];
        float m = fmaxf(fmaxf(e4.x, e4.y), fmaxf(e4.z, e4.w));
        #pragma unroll
        for (int off = 32; off; off >>= 1) m = fmaxf(m, __shfl_xor(m, off));
        const float p0 = __expf(e4.x - m), p1 = __expf(e4.y - m);
        const float p2 = __expf(e4.z - m), p3 = __expf(e4.w - m);
        float s = (p0 + p1) + (p2 + p3);
        #pragma unroll
        for (int off = 32; off; off >>= 1) s += __shfl_xor(s, off);
        const float inv = 1.f / s;
        const float4 pv = {p0 * inv, p1 * inv, p2 * inv, p3 * inv};
        *(float4*)&ep[wv][4 * lane] = pv;
    }
    __syncthreads();

    // ---- phase B: out = attn @ g, j in quarters ----
    const int k = tid & 127, qh = tid >> 7;   // j in [64qh, 64qh+64)
    {
        float o[8] = {0,0,0,0,0,0,0,0};
        const float* gb = g + (b * NN + qh * 64) * HID + k;
        const int jb = qh * 64;
        #pragma unroll 2
        for (int jq = 0; jq < 64; jq += 4) {
            const float g0 = gb[(jq + 0) * HID];
            const float g1 = gb[(jq + 1) * HID];
            const float g2 = gb[(jq + 2) * HID];
            const float g3 = gb[(jq + 3) * HID];
            #pragma unroll
            for (int r = 0; r < 8; ++r) {
                const float4 pv = *(const float4*)&ep[r][jb + jq];
                o[r] += pv.x * g0 + pv.y * g1 + pv.z * g2 + pv.w * g3;
            }
        }
        #pragma unroll
        for (int r = 0; r < 8; ++r) red[qh][r][k] = o[r];
    }
    __syncthreads();

    // ---- final reduce: thread (k,qh) -> rows 2qh, 2qh+1 ----
    {
        const float bo = b_out[k];
        #pragma unroll
        for (int r2 = 0; r2 < 2; ++r2) {
            const int r = 2 * qh + r2;
            out[(b * NN + i0 + r) * HID + k] =
                (red[0][r][k] + red[1][r][k]) +
                (red[2][r][k] + red[3][r][k]) + bo;
        }
    }
}

extern "C" void kernel_launch(void* const* d_in, const int* in_sizes, int n_in,
                              void* d_out, int out_size, void* d_ws, size_t ws_size,
                              hipStream_t stream) {
    const float* x     = (const float*)d_in[0];
    const int*   adj   = (const int*)  d_in[1];
    const float* W_fc  = (const float*)d_in[2];
    const float* b_fc  = (const float*)d_in[3];
    const float* W_a1  = (const float*)d_in[4];
    const float* b_a1  = (const float*)d_in[5];
    const float* w_a2  = (const float*)d_in[6];
    const float* b_a2  = (const float*)d_in[7];
    const float* W_out = (const float*)d_in[8];
    const float* b_out = (const float*)d_in[9];
    float* out = (float*)d_out;

    float* ws  = (float*)d_ws;
    float* aiT = ws;                      // aiT[b][k][n]
    float* ajT = ws + BS * NN * HID;      // ajT[b][k][n]
    float* g   = ws + 2 * BS * NN * HID;  // g = h@W_out, [b][n][k]
    float* hbuf= ws + 3 * BS * NN * HID;  // h, [b][n][k]

    gat_k1a<<<BS * NN / 8, 512, 0, stream>>>(x, W_fc, b_fc, hbuf);
    gat_k1b<<<BS * NN / 8, 512, 0, stream>>>(hbuf, W_a1, b_a1, W_out,
                                             aiT, ajT, g);
    gat_k2<<<BS * (NN / 8), 512, 0, stream>>>(aiT, ajT, g, adj, w_a2, b_a2,
                                              b_out, out);
}

// Round 13
// 47.648 us; speedup vs baseline: 1.5217x; 1.5217x over previous
//
#include <hip/hip_runtime.h>

#define BS  16
#define NN  256
#define HID 128

// 1024 blocks: XCD x gets swz in [128x, 128x+128) = 2 batches.
__device__ __forceinline__ int xcd_swz(int bid) {
    return (bid & 7) * 128 + (bid >> 3);
}

// ---------------------------------------------------------------------------
// K1: 1024 blocks x 512 threads, 4 rows/block, 32 waves/CU. Split-K: thread
// (k, q): phase1/2b quarters of d; phase2a (ai|aj) x d-half. LDS reductions.
// ---------------------------------------------------------------------------
__global__ __launch_bounds__(512, 8) void gat_k1(
    const float* __restrict__ x, const float* __restrict__ W_fc,
    const float* __restrict__ b_fc, const float* __restrict__ W_a1,
    const float* __restrict__ b_a1, const float* __restrict__ W_out,
    float* __restrict__ aiT, float* __restrict__ ajT, float* __restrict__ g)
{
    __shared__ __align__(16) float xs[4][HID];           // 2KB
    __shared__ __align__(16) float hs[4][HID];           // 2KB
    __shared__ __align__(16) float red[4][4][HID];       // 8KB

    const int tid = threadIdx.x;
    const int k   = tid & 127;
    const int q   = tid >> 7;                 // 0..3
    const int swz = xcd_swz(blockIdx.x);
    const int r0  = swz * 4;                  // flat row = b*NN + n0
    const int b   = r0 >> 8;
    const int n0  = r0 & 255;

    xs[q][k] = x[(r0 + q) * HID + k];
    __syncthreads();

    // ---- phase 1: h partials, quarter d in [32q, 32q+32), all 4 rows ----
    {
        float acc[4] = {0, 0, 0, 0};
        const int dq = 32 * q;
        #pragma unroll 2
        for (int d = 0; d < 32; d += 4) {
            float w[4];
            #pragma unroll
            for (int t = 0; t < 4; ++t) w[t] = W_fc[(dq + d + t) * HID + k];
            #pragma unroll
            for (int r = 0; r < 4; ++r) {
                const float4 xv = *(const float4*)&xs[r][dq + d];
                acc[r] += xv.x * w[0] + xv.y * w[1] + xv.z * w[2] + xv.w * w[3];
            }
        }
        #pragma unroll
        for (int r = 0; r < 4; ++r) red[q][r][k] = acc[r];
    }
    __syncthreads();

    // ---- reduce h: thread (k,q) -> row q ----
    hs[q][k] = (red[0][q][k] + red[1][q][k])
             + (red[2][q][k] + red[3][q][k]) + b_fc[k];
    __syncthreads();

    // ---- phase 2a: q = (is_aj, d-half); all 4 rows ----
    {
        const int is_aj = q >> 1;
        const int half  = q & 1;
        const float* Wp = W_a1 + (is_aj * HID + half * 64) * HID;
        float acc[4] = {0, 0, 0, 0};
        const int hb = half * 64;
        #pragma unroll 2
        for (int d = 0; d < 64; d += 4) {
            float w[4];
            #pragma unroll
            for (int t = 0; t < 4; ++t) w[t] = Wp[(d + t) * HID + k];
            #pragma unroll
            for (int r = 0; r < 4; ++r) {
                const float4 hv = *(const float4*)&hs[r][hb + d];
                acc[r] += hv.x * w[0] + hv.y * w[1] + hv.z * w[2] + hv.w * w[3];
            }
        }
        #pragma unroll
        for (int r = 0; r < 4; ++r) red[q][r][k] = acc[r];
    }
    __syncthreads();

    // ---- reduce + transposed store: q0 -> aiT, q2 -> ajT ----
    if (!(q & 1)) {
        const int is_aj = q >> 1;
        const float bias = is_aj ? 0.f : b_a1[k];
        const int p0 = 2 * is_aj, p1 = 2 * is_aj + 1;
        float4 v;
        v.x = red[p0][0][k] + red[p1][0][k] + bias;
        v.y = red[p0][1][k] + red[p1][1][k] + bias;
        v.z = red[p0][2][k] + red[p1][2][k] + bias;
        v.w = red[p0][3][k] + red[p1][3][k] + bias;
        float* dst = (is_aj ? ajT : aiT) + (b * HID + k) * NN + n0;
        *(float4*)dst = v;
    }
    __syncthreads();   // red free again

    // ---- phase 2b: g partials, quarter d in [32q, 32q+32) ----
    {
        float acc[4] = {0, 0, 0, 0};
        const int dq = 32 * q;
        #pragma unroll 2
        for (int d = 0; d < 32; d += 4) {
            float w[4];
            #pragma unroll
            for (int t = 0; t < 4; ++t) w[t] = W_out[(dq + d + t) * HID + k];
            #pragma unroll
            for (int r = 0; r < 4; ++r) {
                const float4 hv = *(const float4*)&hs[r][dq + d];
                acc[r] += hv.x * w[0] + hv.y * w[1] + hv.z * w[2] + hv.w * w[3];
            }
        }
        #pragma unroll
        for (int r = 0; r < 4; ++r) red[q][r][k] = acc[r];
    }
    __syncthreads();

    // ---- reduce g: thread (k,q) -> row q ----
    g[(r0 + q) * HID + k] = (red[0][q][k] + red[1][q][k])
                          + (red[2][q][k] + red[3][q][k]);
}

// ---------------------------------------------------------------------------
// K2: 1024 blocks x 512 threads, 4-row i-tile, 32 waves/CU. Phase A: wave =
// 32 j-cols x 2 row-pairs (lane>>5); hoisted row-independent sum. Softmax
// 1 row/wave (waves 0-3). Phase B: 4-way j-split + LDS reduce.
// ---------------------------------------------------------------------------
__global__ __launch_bounds__(512, 8) void gat_k2(
    const float* __restrict__ aiT, const float* __restrict__ ajT,
    const float* __restrict__ g,  const int* __restrict__ adj,
    const float* __restrict__ w_a2, const float* __restrict__ b_a2,
    const float* __restrict__ b_out, float* __restrict__ out)
{
    __shared__ __align__(16) float aiw[HID][4];          // 2KB, [k][row]
    __shared__ __align__(16) float w2s[HID];
    __shared__ __align__(16) float ep[4][NN];            // 4KB
    __shared__ __align__(16) float red[4][4][HID];       // 8KB

    const int tid = threadIdx.x;
    const int swz = xcd_swz(blockIdx.x);
    const int b   = swz >> 6;
    const int i0  = (swz & 63) * 4;
    const int wv  = tid >> 6, lane = tid & 63;

    if (tid < HID * 4) {
        const int kk = tid >> 2, r = tid & 3;
        aiw[kk][r] = aiT[(b * HID + kk) * NN + i0 + r];
    }
    if (tid >= 384) w2s[tid - 384] = w_a2[tid - 384];
    __syncthreads();

    // ---- phase A: e[4 rows][j], wave covers 32 j x 2 rows per half ----
    const int jj = 32 * wv + (lane & 31);
    const int rg = lane >> 5;                 // rows 2rg, 2rg+1
    {
        int am[2];
        #pragma unroll
        for (int r = 0; r < 2; ++r)
            am[r] = adj[(b * NN + i0 + 2 * rg + r) * NN + jj];

        const float* ajp = ajT + b * HID * NN + jj;
        float acc[2] = {0.f, 0.f};
        float saw = 0.f;                      // sum_k a*wk (row-independent)
        #pragma unroll 8
        for (int kk = 0; kk < HID; ++kk) {
            const float a   = ajp[kk * NN];
            const float2 f2 = *(const float2*)&aiw[kk][2 * rg];
            const float wk  = w2s[kk];
            saw = __builtin_fmaf(a, wk, saw);
            acc[0] = __builtin_fmaf(fmaxf(f2.x, -a), wk, acc[0]);
            acc[1] = __builtin_fmaf(fmaxf(f2.y, -a), wk, acc[1]);
        }
        const float base = saw + b_a2[0];
        #pragma unroll
        for (int r = 0; r < 2; ++r)
            ep[2 * rg + r][jj] = am[r] ? acc[r] + base : -1e9f;
    }
    __syncthreads();

    // ---- softmax: waves 0-3 own rows 0-3 ----
    if (wv < 4) {
        float4 e4 = *(const float4*)&ep[wv][4 * lane];
        float m = fmaxf(fmaxf(e4.x, e4.y), fmaxf(e4.z, e4.w));
        #pragma unroll
        for (int off = 32; off; off >>= 1) m = fmaxf(m, __shfl_xor(m, off));
        const float p0 = __expf(e4.x - m), p1 = __expf(e4.y - m);
        const float p2 = __expf(e4.z - m), p3 = __expf(e4.w - m);
        float s = (p0 + p1) + (p2 + p3);
        #pragma unroll
        for (int off = 32; off; off >>= 1) s += __shfl_xor(s, off);
        const float inv = 1.f / s;
        const float4 pv = {p0 * inv, p1 * inv, p2 * inv, p3 * inv};
        *(float4*)&ep[wv][4 * lane] = pv;
    }
    __syncthreads();

    // ---- phase B: out = attn @ g, j in quarters ----
    const int k = tid & 127, qh = tid >> 7;   // j in [64qh, 64qh+64)
    {
        float o[4] = {0, 0, 0, 0};
        const float* gb = g + (b * NN + qh * 64) * HID + k;
        const int jb = qh * 64;
        #pragma unroll 2
        for (int jq = 0; jq < 64; jq += 4) {
            const float g0 = gb[(jq + 0) * HID];
            const float g1 = gb[(jq + 1) * HID];
            const float g2 = gb[(jq + 2) * HID];
            const float g3 = gb[(jq + 3) * HID];
            #pragma unroll
            for (int r = 0; r < 4; ++r) {
                const float4 pv = *(const float4*)&ep[r][jb + jq];
                o[r] += pv.x * g0 + pv.y * g1 + pv.z * g2 + pv.w * g3;
            }
        }
        #pragma unroll
        for (int r = 0; r < 4; ++r) red[qh][r][k] = o[r];
    }
    __syncthreads();

    // ---- final reduce: thread (k,qh) -> row qh ----
    out[(b * NN + i0 + qh) * HID + k] =
        (red[0][qh][k] + red[1][qh][k]) +
        (red[2][qh][k] + red[3][qh][k]) + b_out[k];
}

extern "C" void kernel_launch(void* const* d_in, const int* in_sizes, int n_in,
                              void* d_out, int out_size, void* d_ws, size_t ws_size,
                              hipStream_t stream) {
    const float* x     = (const float*)d_in[0];
    const int*   adj   = (const int*)  d_in[1];
    const float* W_fc  = (const float*)d_in[2];
    const float* b_fc  = (const float*)d_in[3];
    const float* W_a1  = (const float*)d_in[4];
    const float* b_a1  = (const float*)d_in[5];
    const float* w_a2  = (const float*)d_in[6];
    const float* b_a2  = (const float*)d_in[7];
    const float* W_out = (const float*)d_in[8];
    const float* b_out = (const float*)d_in[9];
    float* out = (float*)d_out;

    float* ws  = (float*)d_ws;
    float* aiT = ws;                      // aiT[b][k][n]
    float* ajT = ws + BS * NN * HID;      // ajT[b][k][n]
    float* g   = ws + 2 * BS * NN * HID;  // g = h@W_out, [b][n][k]

    gat_k1<<<BS * NN / 4, 512, 0, stream>>>(x, W_fc, b_fc, W_a1, b_a1, W_out,
                                            aiT, ajT, g);
    gat_k2<<<BS * (NN / 4), 512, 0, stream>>>(aiT, ajT, g, adj, w_a2, b_a2,
                                              b_out, out);
}

// Round 14
// 42.520 us; speedup vs baseline: 1.7053x; 1.1206x over previous
//
#include <hip/hip_runtime.h>

#define BS  16
#define NN  256
#define HID 128
#define AJS 272   // ajT row stride (floats): 1088B, rotates L2 channels
#define GS  136   // g   row stride (floats):  544B, rotates L2 channels

// 512 blocks: XCD x gets swz in [64x, 64x+64) = batches 2x, 2x+1.
__device__ __forceinline__ int xcd_swz(int bid) {
    return (bid & 7) * 64 + (bid >> 3);
}

// ---------------------------------------------------------------------------
// K1: 512 blocks, 512 threads, 8 rows/block. Split-K quarters; weights read
// once per block; LDS reduction. Identical to R9/R11 except padded strides
// on ajT and g.
// ---------------------------------------------------------------------------
__global__ __launch_bounds__(512, 4) void gat_k1(
    const float* __restrict__ x, const float* __restrict__ W_fc,
    const float* __restrict__ b_fc, const float* __restrict__ W_a1,
    const float* __restrict__ b_a1, const float* __restrict__ W_out,
    float* __restrict__ aiT, float* __restrict__ ajT, float* __restrict__ g)
{
    __shared__ __align__(16) float xs[8][HID];           // 4KB
    __shared__ __align__(16) float hs[8][HID];           // 4KB
    __shared__ __align__(16) float red[4][8][HID];       // 16KB

    const int tid = threadIdx.x;
    const int k   = tid & 127;
    const int q   = tid >> 7;                 // 0..3
    const int swz = xcd_swz(blockIdx.x);
    const int r0  = swz * 8;                  // flat row = b*NN + n0
    const int b   = r0 >> 8;
    const int n0  = r0 & 255;

    for (int t = tid; t < 8 * HID; t += 512)
        xs[t >> 7][t & 127] = x[r0 * HID + t];
    __syncthreads();

    // ---- phase 1: h partials, split-K quarter d in [32q, 32q+32) ----
    {
        float acc[8] = {0,0,0,0,0,0,0,0};
        const int dq = 32 * q;
        #pragma unroll 2
        for (int d = 0; d < 32; d += 4) {
            float w[4];
            #pragma unroll
            for (int t = 0; t < 4; ++t) w[t] = W_fc[(dq + d + t) * HID + k];
            #pragma unroll
            for (int r = 0; r < 8; ++r) {
                const float4 xv = *(const float4*)&xs[r][dq + d];
                acc[r] += xv.x * w[0] + xv.y * w[1] + xv.z * w[2] + xv.w * w[3];
            }
        }
        #pragma unroll
        for (int r = 0; r < 8; ++r) red[q][r][k] = acc[r];
    }
    __syncthreads();

    // ---- reduce h: thread (k,q) -> rows 2q, 2q+1 ----
    {
        const float bf = b_fc[k];
        #pragma unroll
        for (int r2 = 0; r2 < 2; ++r2) {
            const int r = 2 * q + r2;
            hs[r][k] = (red[0][r][k] + red[1][r][k])
                     + (red[2][r][k] + red[3][r][k]) + bf;
        }
    }
    __syncthreads();

    // ---- phase 2a: q0/q1 -> ai d-halves; q2/q3 -> aj d-halves ----
    {
        const int is_aj = q >> 1;
        const int half  = q & 1;
        const float* Wp = W_a1 + (is_aj * HID + half * 64) * HID;
        float acc[8] = {0,0,0,0,0,0,0,0};
        const int hb = half * 64;
        #pragma unroll 2
        for (int d = 0; d < 64; d += 4) {
            float w[4];
            #pragma unroll
            for (int t = 0; t < 4; ++t) w[t] = Wp[(d + t) * HID + k];
            #pragma unroll
            for (int r = 0; r < 8; ++r) {
                const float4 hv = *(const float4*)&hs[r][hb + d];
                acc[r] += hv.x * w[0] + hv.y * w[1] + hv.z * w[2] + hv.w * w[3];
            }
        }
        #pragma unroll
        for (int r = 0; r < 8; ++r) red[q][r][k] = acc[r];
    }
    __syncthreads();

    // ---- reduce + transposed store: q selects (ai|aj, row-quad) ----
    {
        const int is_aj = q >> 1;
        const int rb4   = (q & 1) * 4;
        const float bias = is_aj ? 0.f : b_a1[k];
        const int p0 = 2 * is_aj, p1 = 2 * is_aj + 1;
        float4 v;
        v.x = red[p0][rb4 + 0][k] + red[p1][rb4 + 0][k] + bias;
        v.y = red[p0][rb4 + 1][k] + red[p1][rb4 + 1][k] + bias;
        v.z = red[p0][rb4 + 2][k] + red[p1][rb4 + 2][k] + bias;
        v.w = red[p0][rb4 + 3][k] + red[p1][rb4 + 3][k] + bias;
        if (is_aj) *(float4*)&ajT[(b * HID + k) * AJS + n0 + rb4] = v;
        else       *(float4*)&aiT[(b * HID + k) * NN  + n0 + rb4] = v;
    }
    __syncthreads();   // red free again

    // ---- phase 2b: g partials, split-K quarters ----
    {
        float acc[8] = {0,0,0,0,0,0,0,0};
        const int dq = 32 * q;
        #pragma unroll 2
        for (int d = 0; d < 32; d += 4) {
            float w[4];
            #pragma unroll
            for (int t = 0; t < 4; ++t) w[t] = W_out[(dq + d + t) * HID + k];
            #pragma unroll
            for (int r = 0; r < 8; ++r) {
                const float4 hv = *(const float4*)&hs[r][dq + d];
                acc[r] += hv.x * w[0] + hv.y * w[1] + hv.z * w[2] + hv.w * w[3];
            }
        }
        #pragma unroll
        for (int r = 0; r < 8; ++r) red[q][r][k] = acc[r];
    }
    __syncthreads();

    // ---- reduce g: thread (k,q) -> rows 2q, 2q+1 (padded stride GS) ----
    {
        #pragma unroll
        for (int r2 = 0; r2 < 2; ++r2) {
            const int r = 2 * q + r2;
            g[(r0 + r) * GS + k] = (red[0][r][k] + red[1][r][k])
                                 + (red[2][r][k] + red[3][r][k]);
        }
    }
}

// ---------------------------------------------------------------------------
// K2: 512 blocks, 512 threads, 8-row i-tile (R11 structure, padded strides).
// Phase A: hoisted row-independent sum; softmax 1 row/wave; phase B
// j-quartered with padded-stride g reads.
// ---------------------------------------------------------------------------
__global__ __launch_bounds__(512, 4) void gat_k2(
    const float* __restrict__ aiT, const float* __restrict__ ajT,
    const float* __restrict__ g,  const int* __restrict__ adj,
    const float* __restrict__ w_a2, const float* __restrict__ b_a2,
    const float* __restrict__ b_out, float* __restrict__ out)
{
    __shared__ __align__(16) float aiw[HID][8];          // 4KB, [k][row]
    __shared__ __align__(16) float w2s[HID];
    __shared__ __align__(16) float ep[8][NN];            // 8KB
    __shared__ __align__(16) float red[4][8][HID];       // 16KB

    const int tid = threadIdx.x;
    const int swz = xcd_swz(blockIdx.x);
    const int b   = swz >> 5;
    const int i0  = (swz & 31) * 8;
    const int wv  = tid >> 6, lane = tid & 63;

    for (int t = tid; t < HID * 8; t += 512) {
        const int kk = t >> 3, r = t & 7;
        aiw[kk][r] = aiT[(b * HID + kk) * NN + i0 + r];
    }
    if (tid < HID) w2s[tid] = w_a2[tid];
    __syncthreads();

    // ---- phase A: e[8 rows][j], wave covers 32 j x all 8 rows ----
    const int jj = 32 * wv + (lane & 31);
    const int rg = lane >> 5;                 // rows 4rg .. 4rg+3
    {
        int am[4];
        #pragma unroll
        for (int r = 0; r < 4; ++r)
            am[r] = adj[(b * NN + i0 + 4 * rg + r) * NN + jj];

        const float* ajp = ajT + b * HID * AJS + jj;
        float acc[4] = {0.f, 0.f, 0.f, 0.f};
        float saw = 0.f;                      // sum_k a*wk (row-independent)
        #pragma unroll 8
        for (int kk = 0; kk < HID; ++kk) {
            const float a   = ajp[kk * AJS];
            const float4 f4 = *(const float4*)&aiw[kk][4 * rg];
            const float wk  = w2s[kk];
            saw = __builtin_fmaf(a, wk, saw);
            acc[0] = __builtin_fmaf(fmaxf(f4.x, -a), wk, acc[0]);
            acc[1] = __builtin_fmaf(fmaxf(f4.y, -a), wk, acc[1]);
            acc[2] = __builtin_fmaf(fmaxf(f4.z, -a), wk, acc[2]);
            acc[3] = __builtin_fmaf(fmaxf(f4.w, -a), wk, acc[3]);
        }
        const float base = saw + b_a2[0];
        #pragma unroll
        for (int r = 0; r < 4; ++r)
            ep[4 * rg + r][jj] = am[r] ? acc[r] + base : -1e9f;
    }
    __syncthreads();

    // ---- softmax: wave wv owns row wv ----
    {
        float4 e4 = *(const float4*)&ep[wv][4 * lane];
        float m = fmaxf(fmaxf(e4.x, e4.y), fmaxf(e4.z, e4.w));
        #pragma unroll
        for (int off = 32; off; off >>= 1) m = fmaxf(m, __shfl_xor(m, off));
        const float p0 = __expf(e4.x - m), p1 = __expf(e4.y - m);
        const float p2 = __expf(e4.z - m), p3 = __expf(e4.w - m);
        float s = (p0 + p1) + (p2 + p3);
        #pragma unroll
        for (int off = 32; off; off >>= 1) s += __shfl_xor(s, off);
        const float inv = 1.f / s;
        const float4 pv = {p0 * inv, p1 * inv, p2 * inv, p3 * inv};
        *(float4*)&ep[wv][4 * lane] = pv;
    }
    __syncthreads();

    // ---- phase B: out = attn @ g, j in quarters (padded g stride) ----
    const int k = tid & 127, qh = tid >> 7;   // j in [64qh, 64qh+64)
    {
        float o[8] = {0,0,0,0,0,0,0,0};
        const float* gb = g + (b * NN + qh * 64) * GS + k;
        const int jb = qh * 64;
        #pragma unroll 2
        for (int jq = 0; jq < 64; jq += 4) {
            const float g0 = gb[(jq + 0) * GS];
            const float g1 = gb[(jq + 1) * GS];
            const float g2 = gb[(jq + 2) * GS];
            const float g3 = gb[(jq + 3) * GS];
            #pragma unroll
            for (int r = 0; r < 8; ++r) {
                const float4 pv = *(const float4*)&ep[r][jb + jq];
                o[r] += pv.x * g0 + pv.y * g1 + pv.z * g2 + pv.w * g3;
            }
        }
        #pragma unroll
        for (int r = 0; r < 8; ++r) red[qh][r][k] = o[r];
    }
    __syncthreads();

    // ---- final reduce: thread (k,qh) -> rows 2qh, 2qh+1 ----
    {
        const float bo = b_out[k];
        #pragma unroll
        for (int r2 = 0; r2 < 2; ++r2) {
            const int r = 2 * qh + r2;
            out[(b * NN + i0 + r) * HID + k] =
                (red[0][r][k] + red[1][r][k]) +
                (red[2][r][k] + red[3][r][k]) + bo;
        }
    }
}

extern "C" void kernel_launch(void* const* d_in, const int* in_sizes, int n_in,
                              void* d_out, int out_size, void* d_ws, size_t ws_size,
                              hipStream_t stream) {
    const float* x     = (const float*)d_in[0];
    const int*   adj   = (const int*)  d_in[1];
    const float* W_fc  = (const float*)d_in[2];
    const float* b_fc  = (const float*)d_in[3];
    const float* W_a1  = (const float*)d_in[4];
    const float* b_a1  = (const float*)d_in[5];
    const float* w_a2  = (const float*)d_in[6];
    const float* b_a2  = (const float*)d_in[7];
    const float* W_out = (const float*)d_in[8];
    const float* b_out = (const float*)d_in[9];
    float* out = (float*)d_out;

    float* ws  = (float*)d_ws;
    float* aiT = ws;                               // [b][k][n]   stride NN
    float* ajT = ws + BS * HID * NN;               // [b][k][.]   stride AJS
    float* g   = ws + BS * HID * NN + BS * HID * AJS;  // [b][n][.] stride GS

    gat_k1<<<BS * NN / 8, 512, 0, stream>>>(x, W_fc, b_fc, W_a1, b_a1, W_out,
                                            aiT, ajT, g);
    gat_k2<<<BS * (NN / 8), 512, 0, stream>>>(aiT, ajT, g, adj, w_a2, b_a2,
                                              b_out, out);
}

// Round 15
// 41.536 us; speedup vs baseline: 1.7457x; 1.0237x over previous
//
#include <hip/hip_runtime.h>

#define BS  16
#define NN  256
#define HID 128

// 512 blocks: XCD x gets swz in [64x, 64x+64) = batches 2x, 2x+1.
__device__ __forceinline__ int xcd_swz(int bid) {
    return (bid & 7) * 64 + (bid >> 3);
}

// ---------------------------------------------------------------------------
// K1: 512 blocks, 512 threads, 8 rows/block. Split-K quarters; weights read
// once per block; LDS reduction. (Exact R9 configuration — best measured.)
// ---------------------------------------------------------------------------
__global__ __launch_bounds__(512, 4) void gat_k1(
    const float* __restrict__ x, const float* __restrict__ W_fc,
    const float* __restrict__ b_fc, const float* __restrict__ W_a1,
    const float* __restrict__ b_a1, const float* __restrict__ W_out,
    float* __restrict__ aiT, float* __restrict__ ajT, float* __restrict__ g)
{
    __shared__ __align__(16) float xs[8][HID];           // 4KB
    __shared__ __align__(16) float hs[8][HID];           // 4KB
    __shared__ __align__(16) float red[4][8][HID];       // 16KB

    const int tid = threadIdx.x;
    const int k   = tid & 127;
    const int q   = tid >> 7;                 // 0..3
    const int swz = xcd_swz(blockIdx.x);
    const int r0  = swz * 8;                  // flat row = b*NN + n0
    const int b   = r0 >> 8;
    const int n0  = r0 & 255;

    for (int t = tid; t < 8 * HID; t += 512)
        xs[t >> 7][t & 127] = x[r0 * HID + t];
    __syncthreads();

    // ---- phase 1: h partials, split-K quarter d in [32q, 32q+32) ----
    {
        float acc[8] = {0,0,0,0,0,0,0,0};
        const int dq = 32 * q;
        #pragma unroll 2
        for (int d = 0; d < 32; d += 4) {
            float w[4];
            #pragma unroll
            for (int t = 0; t < 4; ++t) w[t] = W_fc[(dq + d + t) * HID + k];
            #pragma unroll
            for (int r = 0; r < 8; ++r) {
                const float4 xv = *(const float4*)&xs[r][dq + d];
                acc[r] += xv.x * w[0] + xv.y * w[1] + xv.z * w[2] + xv.w * w[3];
            }
        }
        #pragma unroll
        for (int r = 0; r < 8; ++r) red[q][r][k] = acc[r];
    }
    __syncthreads();

    // ---- reduce h: thread (k,q) -> rows 2q, 2q+1 ----
    {
        const float bf = b_fc[k];
        #pragma unroll
        for (int r2 = 0; r2 < 2; ++r2) {
            const int r = 2 * q + r2;
            hs[r][k] = (red[0][r][k] + red[1][r][k])
                     + (red[2][r][k] + red[3][r][k]) + bf;
        }
    }
    __syncthreads();

    // ---- phase 2a: q0/q1 -> ai d-halves; q2/q3 -> aj d-halves ----
    {
        const int is_aj = q >> 1;
        const int half  = q & 1;
        const float* Wp = W_a1 + (is_aj * HID + half * 64) * HID;
        float acc[8] = {0,0,0,0,0,0,0,0};
        const int hb = half * 64;
        #pragma unroll 2
        for (int d = 0; d < 64; d += 4) {
            float w[4];
            #pragma unroll
            for (int t = 0; t < 4; ++t) w[t] = Wp[(d + t) * HID + k];
            #pragma unroll
            for (int r = 0; r < 8; ++r) {
                const float4 hv = *(const float4*)&hs[r][hb + d];
                acc[r] += hv.x * w[0] + hv.y * w[1] + hv.z * w[2] + hv.w * w[3];
            }
        }
        #pragma unroll
        for (int r = 0; r < 8; ++r) red[q][r][k] = acc[r];
    }
    __syncthreads();

    // ---- reduce + transposed store: q selects (ai|aj, row-quad) ----
    {
        const int is_aj = q >> 1;
        const int rb4   = (q & 1) * 4;
        const float bias = is_aj ? 0.f : b_a1[k];
        const int p0 = 2 * is_aj, p1 = 2 * is_aj + 1;
        float4 v;
        v.x = red[p0][rb4 + 0][k] + red[p1][rb4 + 0][k] + bias;
        v.y = red[p0][rb4 + 1][k] + red[p1][rb4 + 1][k] + bias;
        v.z = red[p0][rb4 + 2][k] + red[p1][rb4 + 2][k] + bias;
        v.w = red[p0][rb4 + 3][k] + red[p1][rb4 + 3][k] + bias;
        float* dst = (is_aj ? ajT : aiT) + (b * HID + k) * NN + n0 + rb4;
        *(float4*)dst = v;
    }
    __syncthreads();   // red free again

    // ---- phase 2b: g partials, split-K quarters ----
    {
        float acc[8] = {0,0,0,0,0,0,0,0};
        const int dq = 32 * q;
        #pragma unroll 2
        for (int d = 0; d < 32; d += 4) {
            float w[4];
            #pragma unroll
            for (int t = 0; t < 4; ++t) w[t] = W_out[(dq + d + t) * HID + k];
            #pragma unroll
            for (int r = 0; r < 8; ++r) {
                const float4 hv = *(const float4*)&hs[r][dq + d];
                acc[r] += hv.x * w[0] + hv.y * w[1] + hv.z * w[2] + hv.w * w[3];
            }
        }
        #pragma unroll
        for (int r = 0; r < 8; ++r) red[q][r][k] = acc[r];
    }
    __syncthreads();

    // ---- reduce g: thread (k,q) -> rows 2q, 2q+1 ----
    {
        #pragma unroll
        for (int r2 = 0; r2 < 2; ++r2) {
            const int r = 2 * q + r2;
            g[(r0 + r) * HID + k] = (red[0][r][k] + red[1][r][k])
                                  + (red[2][r][k] + red[3][r][k]);
        }
    }
}

// ---------------------------------------------------------------------------
// K2: 512 blocks, 512 threads, 8-row i-tile. Phase A NEW: wave = (k-half kh,
// row-pair rp); lane l loads ajT[kk][4l..4l+3] as FLOAT4 (16B/lane, one
// wave-request covers a full 256-j slab row; 64 iters instead of 128).
// k-half partials reduced via LDS. Softmax 1 row/wave; phase B j-quartered.
// ---------------------------------------------------------------------------
__global__ __launch_bounds__(512, 4) void gat_k2(
    const float* __restrict__ aiT, const float* __restrict__ ajT,
    const float* __restrict__ g,  const int* __restrict__ adj,
    const float* __restrict__ w_a2, const float* __restrict__ b_a2,
    const float* __restrict__ b_out, float* __restrict__ out)
{
    __shared__ __align__(16) float aiw[HID][8];          // 4KB, [k][row]
    __shared__ __align__(16) float w2s[HID];             // 0.5KB
    __shared__ __align__(16) float buf[2][8][NN];        // 16KB: e-halves; red
    __shared__ __align__(16) float ep[8][NN];            // 8KB: p

    const int tid = threadIdx.x;
    const int swz = xcd_swz(blockIdx.x);
    const int b   = swz >> 5;
    const int i0  = (swz & 31) * 8;
    const int wv  = tid >> 6, lane = tid & 63;

    for (int t = tid; t < HID * 8; t += 512) {
        const int kk = t >> 3, r = t & 7;
        aiw[kk][r] = aiT[(b * HID + kk) * NN + i0 + r];
    }
    if (tid < HID) w2s[tid] = w_a2[tid];

    // adj prefetch in softmax layout (row wv, cols 4*lane..+3)
    const int4 am = *(const int4*)(adj + (b * NN + i0 + wv) * NN + 4 * lane);
    __syncthreads();

    // ---- phase A: wave (kh, rp): rows 2rp,2rp+1; kk in [64kh,64kh+64);
    //      lane l owns j = 4l..4l+3 via one float4 load per kk ----
    const int kh = wv >> 2, rp = wv & 3;
    {
        const float* ajp = ajT + (b * HID + kh * 64) * NN + 4 * lane;
        float4 acc0 = {0,0,0,0}, acc1 = {0,0,0,0}, saw = {0,0,0,0};
        const int kb = kh * 64;
        #pragma unroll 8
        for (int t = 0; t < 64; ++t) {
            const float4 a4 = *(const float4*)(ajp + t * NN);
            const float2 f2 = *(const float2*)&aiw[kb + t][2 * rp];
            const float wk  = w2s[kb + t];
            saw.x  = __builtin_fmaf(a4.x, wk, saw.x);
            saw.y  = __builtin_fmaf(a4.y, wk, saw.y);
            saw.z  = __builtin_fmaf(a4.z, wk, saw.z);
            saw.w  = __builtin_fmaf(a4.w, wk, saw.w);
            acc0.x = __builtin_fmaf(fmaxf(f2.x, -a4.x), wk, acc0.x);
            acc0.y = __builtin_fmaf(fmaxf(f2.x, -a4.y), wk, acc0.y);
            acc0.z = __builtin_fmaf(fmaxf(f2.x, -a4.z), wk, acc0.z);
            acc0.w = __builtin_fmaf(fmaxf(f2.x, -a4.w), wk, acc0.w);
            acc1.x = __builtin_fmaf(fmaxf(f2.y, -a4.x), wk, acc1.x);
            acc1.y = __builtin_fmaf(fmaxf(f2.y, -a4.y), wk, acc1.y);
            acc1.z = __builtin_fmaf(fmaxf(f2.y, -a4.z), wk, acc1.z);
            acc1.w = __builtin_fmaf(fmaxf(f2.y, -a4.w), wk, acc1.w);
        }
        // fold saw (per-j) into each row's partial, store to e-half buffer
        const float4 e0 = {acc0.x + saw.x, acc0.y + saw.y,
                           acc0.z + saw.z, acc0.w + saw.w};
        const float4 e1 = {acc1.x + saw.x, acc1.y + saw.y,
                           acc1.z + saw.z, acc1.w + saw.w};
        *(float4*)&buf[kh][2 * rp + 0][4 * lane] = e0;
        *(float4*)&buf[kh][2 * rp + 1][4 * lane] = e1;
    }
    __syncthreads();

    // ---- mask + softmax: wave wv owns row wv ----
    {
        const float ba2 = b_a2[0];
        const float4 u = *(const float4*)&buf[0][wv][4 * lane];
        const float4 v = *(const float4*)&buf[1][wv][4 * lane];
        const float e0 = am.x ? u.x + v.x + ba2 : -1e9f;
        const float e1 = am.y ? u.y + v.y + ba2 : -1e9f;
        const float e2 = am.z ? u.z + v.z + ba2 : -1e9f;
        const float e3 = am.w ? u.w + v.w + ba2 : -1e9f;
        float m = fmaxf(fmaxf(e0, e1), fmaxf(e2, e3));
        #pragma unroll
        for (int off = 32; off; off >>= 1) m = fmaxf(m, __shfl_xor(m, off));
        const float p0 = __expf(e0 - m), p1 = __expf(e1 - m);
        const float p2 = __expf(e2 - m), p3 = __expf(e3 - m);
        float s = (p0 + p1) + (p2 + p3);
        #pragma unroll
        for (int off = 32; off; off >>= 1) s += __shfl_xor(s, off);
        const float inv = 1.f / s;
        const float4 pv = {p0 * inv, p1 * inv, p2 * inv, p3 * inv};
        *(float4*)&ep[wv][4 * lane] = pv;
    }
    __syncthreads();

    // ---- phase B: out = attn @ g, j in quarters (red aliases buf) ----
    float* red = &buf[0][0][0];               // [4][8][HID] = 16KB
    const int k = tid & 127, qh = tid >> 7;   // j in [64qh, 64qh+64)
    {
        float o[8] = {0,0,0,0,0,0,0,0};
        const float* gb = g + (b * NN + qh * 64) * HID + k;
        const int jb = qh * 64;
        #pragma unroll 2
        for (int jq = 0; jq < 64; jq += 4) {
            const float g0 = gb[(jq + 0) * HID];
            const float g1 = gb[(jq + 1) * HID];
            const float g2 = gb[(jq + 2) * HID];
            const float g3 = gb[(jq + 3) * HID];
            #pragma unroll
            for (int r = 0; r < 8; ++r) {
                const float4 pv = *(const float4*)&ep[r][jb + jq];
                o[r] += pv.x * g0 + pv.y * g1 + pv.z * g2 + pv.w * g3;
            }
        }
        #pragma unroll
        for (int r = 0; r < 8; ++r) red[(qh * 8 + r) * HID + k] = o[r];
    }
    __syncthreads();

    // ---- final reduce: thread (k,qh) -> rows 2qh, 2qh+1 ----
    {
        const float bo = b_out[k];
        #pragma unroll
        for (int r2 = 0; r2 < 2; ++r2) {
            const int r = 2 * qh + r2;
            out[(b * NN + i0 + r) * HID + k] =
                (red[(0 + r) * HID + k]  + red[(8 + r) * HID + k]) +
                (red[(16 + r) * HID + k] + red[(24 + r) * HID + k]) + bo;
        }
    }
}

extern "C" void kernel_launch(void* const* d_in, const int* in_sizes, int n_in,
                              void* d_out, int out_size, void* d_ws, size_t ws_size,
                              hipStream_t stream) {
    const float* x     = (const float*)d_in[0];
    const int*   adj   = (const int*)  d_in[1];
    const float* W_fc  = (const float*)d_in[2];
    const float* b_fc  = (const float*)d_in[3];
    const float* W_a1  = (const float*)d_in[4];
    const float* b_a1  = (const float*)d_in[5];
    const float* w_a2  = (const float*)d_in[6];
    const float* b_a2  = (const float*)d_in[7];
    const float* W_out = (const float*)d_in[8];
    const float* b_out = (const float*)d_in[9];
    float* out = (float*)d_out;

    float* ws  = (float*)d_ws;
    float* aiT = ws;                      // aiT[b][k][n]
    float* ajT = ws + BS * NN * HID;      // ajT[b][k][n]
    float* g   = ws + 2 * BS * NN * HID;  // g = h@W_out, [b][n][k]

    gat_k1<<<BS * NN / 8, 512, 0, stream>>>(x, W_fc, b_fc, W_a1, b_a1, W_out,
                                            aiT, ajT, g);
    gat_k2<<<BS * (NN / 8), 512, 0, stream>>>(aiT, ajT, g, adj, w_a2, b_a2,
                                              b_out, out);
}

// Round 16
// 40.860 us; speedup vs baseline: 1.7745x; 1.0165x over previous
//
#include <hip/hip_runtime.h>

#define BS  16
#define NN  256
#define HID 128

// 512 blocks: XCD x gets swz in [64x, 64x+64) = batches 2x, 2x+1.
__device__ __forceinline__ int xcd_swz(int bid) {
    return (bid & 7) * 64 + (bid >> 3);
}

// ---------------------------------------------------------------------------
// K1: 512 blocks, 512 threads, 8 rows/block. Split-K quarters. Phase 2 FUSED:
// one hs read stream feeds ai+aj+g accumulators (LDS broadcasts 256->128 per
// wave). red[4][3][8][128] = 48KB; 56KB total -> 2 blocks/CU.
// ---------------------------------------------------------------------------
__global__ __launch_bounds__(512, 4) void gat_k1(
    const float* __restrict__ x, const float* __restrict__ W_fc,
    const float* __restrict__ b_fc, const float* __restrict__ W_a1,
    const float* __restrict__ b_a1, const float* __restrict__ W_out,
    float* __restrict__ aiT, float* __restrict__ ajT, float* __restrict__ g)
{
    __shared__ __align__(16) float xs[8][HID];            // 4KB
    __shared__ __align__(16) float hs[8][HID];            // 4KB
    __shared__ __align__(16) float red[4][3][8][HID];     // 48KB

    const int tid = threadIdx.x;
    const int k   = tid & 127;
    const int q   = tid >> 7;                 // 0..3
    const int swz = xcd_swz(blockIdx.x);
    const int r0  = swz * 8;                  // flat row = b*NN + n0
    const int b   = r0 >> 8;
    const int n0  = r0 & 255;

    for (int t = tid; t < 8 * HID; t += 512)
        xs[t >> 7][t & 127] = x[r0 * HID + t];
    __syncthreads();

    // ---- phase 1: h partials, split-K quarter d in [32q, 32q+32) ----
    {
        float acc[8] = {0,0,0,0,0,0,0,0};
        const int dq = 32 * q;
        #pragma unroll 2
        for (int d = 0; d < 32; d += 4) {
            float w[4];
            #pragma unroll
            for (int t = 0; t < 4; ++t) w[t] = W_fc[(dq + d + t) * HID + k];
            #pragma unroll
            for (int r = 0; r < 8; ++r) {
                const float4 xv = *(const float4*)&xs[r][dq + d];
                acc[r] += xv.x * w[0] + xv.y * w[1] + xv.z * w[2] + xv.w * w[3];
            }
        }
        #pragma unroll
        for (int r = 0; r < 8; ++r) red[q][0][r][k] = acc[r];
    }
    __syncthreads();

    // ---- reduce h: thread (k,q) -> rows 2q, 2q+1 ----
    {
        const float bf = b_fc[k];
        #pragma unroll
        for (int r2 = 0; r2 < 2; ++r2) {
            const int r = 2 * q + r2;
            hs[r][k] = (red[0][0][r][k] + red[1][0][r][k])
                     + (red[2][0][r][k] + red[3][0][r][k]) + bf;
        }
    }
    __syncthreads();

    // ---- phase 2 FUSED: ai+aj+g partials over d-quarter, one hs stream ----
    {
        float ai_a[8] = {0,0,0,0,0,0,0,0};
        float aj_a[8] = {0,0,0,0,0,0,0,0};
        float g_a[8]  = {0,0,0,0,0,0,0,0};
        const int dq = 32 * q;
        #pragma unroll 2
        for (int d = 0; d < 32; d += 4) {
            float wi[4], wj[4], wo[4];
            #pragma unroll
            for (int t = 0; t < 4; ++t) {
                wi[t] = W_a1[(dq + d + t) * HID + k];
                wj[t] = W_a1[(HID + dq + d + t) * HID + k];
                wo[t] = W_out[(dq + d + t) * HID + k];
            }
            #pragma unroll
            for (int r = 0; r < 8; ++r) {
                const float4 hv = *(const float4*)&hs[r][dq + d];
                ai_a[r] += hv.x * wi[0] + hv.y * wi[1] + hv.z * wi[2] + hv.w * wi[3];
                aj_a[r] += hv.x * wj[0] + hv.y * wj[1] + hv.z * wj[2] + hv.w * wj[3];
                g_a[r]  += hv.x * wo[0] + hv.y * wo[1] + hv.z * wo[2] + hv.w * wo[3];
            }
        }
        #pragma unroll
        for (int r = 0; r < 8; ++r) {
            red[q][0][r][k] = ai_a[r];
            red[q][1][r][k] = aj_a[r];
            red[q][2][r][k] = g_a[r];
        }
    }
    __syncthreads();

    // ---- reduce + stores ----
    {
        // ai/aj transposed: q selects (proj, row-quad)
        const int is_aj = q >> 1;
        const int rb4   = (q & 1) * 4;
        const float bias = is_aj ? 0.f : b_a1[k];
        float4 v;
        v.x = (red[0][is_aj][rb4 + 0][k] + red[1][is_aj][rb4 + 0][k])
            + (red[2][is_aj][rb4 + 0][k] + red[3][is_aj][rb4 + 0][k]) + bias;
        v.y = (red[0][is_aj][rb4 + 1][k] + red[1][is_aj][rb4 + 1][k])
            + (red[2][is_aj][rb4 + 1][k] + red[3][is_aj][rb4 + 1][k]) + bias;
        v.z = (red[0][is_aj][rb4 + 2][k] + red[1][is_aj][rb4 + 2][k])
            + (red[2][is_aj][rb4 + 2][k] + red[3][is_aj][rb4 + 2][k]) + bias;
        v.w = (red[0][is_aj][rb4 + 3][k] + red[1][is_aj][rb4 + 3][k])
            + (red[2][is_aj][rb4 + 3][k] + red[3][is_aj][rb4 + 3][k]) + bias;
        float* dst = (is_aj ? ajT : aiT) + (b * HID + k) * NN + n0 + rb4;
        *(float4*)dst = v;

        // g rows 2q, 2q+1
        #pragma unroll
        for (int r2 = 0; r2 < 2; ++r2) {
            const int r = 2 * q + r2;
            g[(r0 + r) * HID + k] = (red[0][2][r][k] + red[1][2][r][k])
                                  + (red[2][2][r][k] + red[3][2][r][k]);
        }
    }
}

// ---------------------------------------------------------------------------
// K2: exact R15. 512 blocks, 512 threads, 8-row i-tile. Phase A: wave =
// (k-half, row-pair), float4 aj loads; k-half partials via LDS. Softmax
// 1 row/wave; phase B j-quartered.
// ---------------------------------------------------------------------------
__global__ __launch_bounds__(512, 4) void gat_k2(
    const float* __restrict__ aiT, const float* __restrict__ ajT,
    const float* __restrict__ g,  const int* __restrict__ adj,
    const float* __restrict__ w_a2, const float* __restrict__ b_a2,
    const float* __restrict__ b_out, float* __restrict__ out)
{
    __shared__ __align__(16) float aiw[HID][8];          // 4KB, [k][row]
    __shared__ __align__(16) float w2s[HID];             // 0.5KB
    __shared__ __align__(16) float buf[2][8][NN];        // 16KB: e-halves; red
    __shared__ __align__(16) float ep[8][NN];            // 8KB: p

    const int tid = threadIdx.x;
    const int swz = xcd_swz(blockIdx.x);
    const int b   = swz >> 5;
    const int i0  = (swz & 31) * 8;
    const int wv  = tid >> 6, lane = tid & 63;

    for (int t = tid; t < HID * 8; t += 512) {
        const int kk = t >> 3, r = t & 7;
        aiw[kk][r] = aiT[(b * HID + kk) * NN + i0 + r];
    }
    if (tid < HID) w2s[tid] = w_a2[tid];

    // adj prefetch in softmax layout (row wv, cols 4*lane..+3)
    const int4 am = *(const int4*)(adj + (b * NN + i0 + wv) * NN + 4 * lane);
    __syncthreads();

    // ---- phase A: wave (kh, rp): rows 2rp,2rp+1; kk in [64kh,64kh+64) ----
    const int kh = wv >> 2, rp = wv & 3;
    {
        const float* ajp = ajT + (b * HID + kh * 64) * NN + 4 * lane;
        float4 acc0 = {0,0,0,0}, acc1 = {0,0,0,0}, saw = {0,0,0,0};
        const int kb = kh * 64;
        #pragma unroll 8
        for (int t = 0; t < 64; ++t) {
            const float4 a4 = *(const float4*)(ajp + t * NN);
            const float2 f2 = *(const float2*)&aiw[kb + t][2 * rp];
            const float wk  = w2s[kb + t];
            saw.x  = __builtin_fmaf(a4.x, wk, saw.x);
            saw.y  = __builtin_fmaf(a4.y, wk, saw.y);
            saw.z  = __builtin_fmaf(a4.z, wk, saw.z);
            saw.w  = __builtin_fmaf(a4.w, wk, saw.w);
            acc0.x = __builtin_fmaf(fmaxf(f2.x, -a4.x), wk, acc0.x);
            acc0.y = __builtin_fmaf(fmaxf(f2.x, -a4.y), wk, acc0.y);
            acc0.z = __builtin_fmaf(fmaxf(f2.x, -a4.z), wk, acc0.z);
            acc0.w = __builtin_fmaf(fmaxf(f2.x, -a4.w), wk, acc0.w);
            acc1.x = __builtin_fmaf(fmaxf(f2.y, -a4.x), wk, acc1.x);
            acc1.y = __builtin_fmaf(fmaxf(f2.y, -a4.y), wk, acc1.y);
            acc1.z = __builtin_fmaf(fmaxf(f2.y, -a4.z), wk, acc1.z);
            acc1.w = __builtin_fmaf(fmaxf(f2.y, -a4.w), wk, acc1.w);
        }
        const float4 e0 = {acc0.x + saw.x, acc0.y + saw.y,
                           acc0.z + saw.z, acc0.w + saw.w};
        const float4 e1 = {acc1.x + saw.x, acc1.y + saw.y,
                           acc1.z + saw.z, acc1.w + saw.w};
        *(float4*)&buf[kh][2 * rp + 0][4 * lane] = e0;
        *(float4*)&buf[kh][2 * rp + 1][4 * lane] = e1;
    }
    __syncthreads();

    // ---- mask + softmax: wave wv owns row wv ----
    {
        const float ba2 = b_a2[0];
        const float4 u = *(const float4*)&buf[0][wv][4 * lane];
        const float4 v = *(const float4*)&buf[1][wv][4 * lane];
        const float e0 = am.x ? u.x + v.x + ba2 : -1e9f;
        const float e1 = am.y ? u.y + v.y + ba2 : -1e9f;
        const float e2 = am.z ? u.z + v.z + ba2 : -1e9f;
        const float e3 = am.w ? u.w + v.w + ba2 : -1e9f;
        float m = fmaxf(fmaxf(e0, e1), fmaxf(e2, e3));
        #pragma unroll
        for (int off = 32; off; off >>= 1) m = fmaxf(m, __shfl_xor(m, off));
        const float p0 = __expf(e0 - m), p1 = __expf(e1 - m);
        const float p2 = __expf(e2 - m), p3 = __expf(e3 - m);
        float s = (p0 + p1) + (p2 + p3);
        #pragma unroll
        for (int off = 32; off; off >>= 1) s += __shfl_xor(s, off);
        const float inv = 1.f / s;
        const float4 pv = {p0 * inv, p1 * inv, p2 * inv, p3 * inv};
        *(float4*)&ep[wv][4 * lane] = pv;
    }
    __syncthreads();

    // ---- phase B: out = attn @ g, j in quarters (red aliases buf) ----
    float* red = &buf[0][0][0];               // [4][8][HID] = 16KB
    const int k = tid & 127, qh = tid >> 7;   // j in [64qh, 64qh+64)
    {
        float o[8] = {0,0,0,0,0,0,0,0};
        const float* gb = g + (b * NN + qh * 64) * HID + k;
        const int jb = qh * 64;
        #pragma unroll 2
        for (int jq = 0; jq < 64; jq += 4) {
            const float g0 = gb[(jq + 0) * HID];
            const float g1 = gb[(jq + 1) * HID];
            const float g2 = gb[(jq + 2) * HID];
            const float g3 = gb[(jq + 3) * HID];
            #pragma unroll
            for (int r = 0; r < 8; ++r) {
                const float4 pv = *(const float4*)&ep[r][jb + jq];
                o[r] += pv.x * g0 + pv.y * g1 + pv.z * g2 + pv.w * g3;
            }
        }
        #pragma unroll
        for (int r = 0; r < 8; ++r) red[(qh * 8 + r) * HID + k] = o[r];
    }
    __syncthreads();

    // ---- final reduce: thread (k,qh) -> rows 2qh, 2qh+1 ----
    {
        const float bo = b_out[k];
        #pragma unroll
        for (int r2 = 0; r2 < 2; ++r2) {
            const int r = 2 * qh + r2;
            out[(b * NN + i0 + r) * HID + k] =
                (red[(0 + r) * HID + k]  + red[(8 + r) * HID + k]) +
                (red[(16 + r) * HID + k] + red[(24 + r) * HID + k]) + bo;
        }
    }
}

extern "C" void kernel_launch(void* const* d_in, const int* in_sizes, int n_in,
                              void* d_out, int out_size, void* d_ws, size_t ws_size,
                              hipStream_t stream) {
    const float* x     = (const float*)d_in[0];
    const int*   adj   = (const int*)  d_in[1];
    const float* W_fc  = (const float*)d_in[2];
    const float* b_fc  = (const float*)d_in[3];
    const float* W_a1  = (const float*)d_in[4];
    const float* b_a1  = (const float*)d_in[5];
    const float* w_a2  = (const float*)d_in[6];
    const float* b_a2  = (const float*)d_in[7];
    const float* W_out = (const float*)d_in[8];
    const float* b_out = (const float*)d_in[9];
    float* out = (float*)d_out;

    float* ws  = (float*)d_ws;
    float* aiT = ws;                      // aiT[b][k][n]
    float* ajT = ws + BS * NN * HID;      // ajT[b][k][n]
    float* g   = ws + 2 * BS * NN * HID;  // g = h@W_out, [b][n][k]

    gat_k1<<<BS * NN / 8, 512, 0, stream>>>(x, W_fc, b_fc, W_a1, b_a1, W_out,
                                            aiT, ajT, g);
    gat_k2<<<BS * (NN / 8), 512, 0, stream>>>(aiT, ajT, g, adj, w_a2, b_a2,
                                              b_out, out);
}